// Round 2
// 329.779 us; speedup vs baseline: 1.0270x; 1.0270x over previous
//
#include <hip/hip_runtime.h>
#include <cstdint>
#include <cstddef>

// ONLSTM cell: B=4096, D=1024, U=1024.
// pre16 = fp16([X|H] @ [[W_all],[U_all]] + b_all), single-fp16 MFMA.
// R1-R6 history: absmax (0.25) dominated by fp32 softmax/cumsum path; threshold 1.55.
// R7: GEMM rewritten to 8-phase/counted-vmcnt pipeline (T2+T3+T4+T5+T1):
//   - 128x256 tile, BK=64, 512 thr (8 waves 2x4), grid 768 = 3 rounds/CU exact.
//   - half-tile LDS ring (A-half 64x64, B-half 128x64; 2 bufs = 96 KB): each phase
//     computes one (mh,nh) quadrant (8 MFMA) + stages one future half-tile into a
//     region last read >=1 barrier ago -> K-tile boundary waits vmcnt(3), NEVER 0.
//   - raw s_barrier in main loop (no __syncthreads: drains vmcnt(0), caps ~34%).
//   - 3-bit XOR slot swizzle (slot ^= row&7) via pre-swizzled global source
//     (global_load_lds dest must stay linear) -> b128 frag reads at bank floor.
//   - setprio(1) around MFMA cluster; bijective XCD swizzle (768%8==0).
// R8 (this round): R7 bench was an infra failure (container died twice; audit
// found no hang/fault path). Resubmitted with one latent race fixed: epilogue
// LDS-stage barrier is now __syncthreads() (lgkmcnt(0)+s_barrier) so ds_writes
// drain before cross-wave reads. vmcnt is already 0 there, so no perf cost.

typedef _Float16 half8  __attribute__((ext_vector_type(8)));
typedef _Float16 half4v __attribute__((ext_vector_type(4)));
typedef float f32x4 __attribute__((ext_vector_type(4)));

__device__ __forceinline__ void async16(const _Float16* g, _Float16* l) {
  __builtin_amdgcn_global_load_lds(
      (const __attribute__((address_space(1))) void*)g,
      (__attribute__((address_space(3))) void*)l, 16, 0, 0);
}

struct Ptrs12 { const float* p[12]; };
struct Ptrs6  { const float* p[6];  };

// ---------------------------------------------------------------------------
// Merged prep: convert A (X|H -> fp16), convert+transpose B (x64 scale, fp16),
// build bias. Branch is block-uniform. (unchanged from R6)
__global__ void prep(const float* __restrict__ X, const float* __restrict__ H,
                     Ptrs12 w, Ptrs6 bs,
                     _Float16* __restrict__ Ahi, _Float16* __restrict__ Bhi,
                     float* __restrict__ b_all) {
  __shared__ float tile[64][65];
  const int blk = blockIdx.x;
  const int t = threadIdx.x;
  if (blk < 8192) {
    size_t base = ((size_t)blk * 256 + t) * 4;
    int k = (int)(base & 2047);
    size_t b = base >> 11;
    const float* src = (k < 1024) ? (X + b * 1024 + k) : (H + b * 1024 + (k - 1024));
    float4 v = *(const float4*)src;
    half4v hi = { (_Float16)v.x, (_Float16)v.y, (_Float16)v.z, (_Float16)v.w };
    *(half4v*)(Ahi + base) = hi;
  } else if (blk < 11264) {
    int bb = blk - 8192;
    int mat = bb >> 8;
    int tl = bb & 255;
    int tr = tl >> 4, tc = tl & 15;
    int g = mat >> 1, s = mat & 1;
    const float* src = w.p[mat];
    int col = t & 63, r0 = t >> 6;
#pragma unroll
    for (int i = 0; i < 16; i++) {
      int row = i * 4 + r0;
      tile[row][col] = src[(size_t)(tr * 64 + row) * 1024 + tc * 64 + col];
    }
    __syncthreads();
    int c2 = t >> 2, kseg = t & 3;
    half8 v0, v1;
#pragma unroll
    for (int j = 0; j < 8; j++) {
      v0[j] = (_Float16)(tile[kseg * 16 + j][c2] * 64.0f);
      v1[j] = (_Float16)(tile[kseg * 16 + 8 + j][c2] * 64.0f);
    }
    size_t n  = (size_t)g * 1024 + tc * 64 + c2;
    size_t kk = (size_t)s * 1024 + tr * 64 + kseg * 16;
    *(half8*)(Bhi + n * 2048 + kk) = v0;
    *(half8*)(Bhi + n * 2048 + kk + 8) = v1;
  } else {
    int n = (blk - 11264) * 256 + t;
    b_all[n] = bs.p[n >> 10][n & 1023];
  }
}

// ---------------------------------------------------------------------------
// GEMM: A[4096,2048] @ Bt[6144,2048]^T / 64 + bias -> pre16 (fp16, row-major).
// 8-phase counted-vmcnt pipeline; see header comment.

#define LGKM0 asm volatile("s_waitcnt lgkmcnt(0)" ::: "memory")

__device__ __forceinline__ void wg_barrier() {
  __builtin_amdgcn_s_barrier();
  asm volatile("" ::: "memory");
}

// One phase: ds_read quadrant (MH,NH) frags, issue STAGE, fence reads, barrier,
// MFMA the quadrant. WAIT_STMT = optional vmcnt at the K-tile boundary (p3).
#define PHASE(TT, MH, NH, STAGE_STMT, WAIT_STMT)                               \
  {                                                                            \
    const _Float16* bufA_ = lds + ((TT) & 1) * 24576 + (MH) * 4096;            \
    const _Float16* bufB_ = lds + ((TT) & 1) * 24576 + 8192 + (NH) * 8192;     \
    half8 af[2][2], bf[2][2];                                                  \
    _Pragma("unroll")                                                          \
    for (int f = 0; f < 2; f++) {                                              \
      int r = wm * 32 + f * 16 + frow;                                         \
      _Pragma("unroll")                                                        \
      for (int ks = 0; ks < 2; ks++)                                           \
        af[f][ks] = *(const half8*)(bufA_ + r * 64 +                           \
                                    (((ks * 4 + kgrp) ^ (r & 7)) * 8));        \
    }                                                                          \
    _Pragma("unroll")                                                          \
    for (int g = 0; g < 2; g++) {                                              \
      int r = wn * 32 + g * 16 + frow;                                         \
      _Pragma("unroll")                                                        \
      for (int ks = 0; ks < 2; ks++)                                           \
        bf[g][ks] = *(const half8*)(bufB_ + r * 64 +                           \
                                    (((ks * 4 + kgrp) ^ (r & 7)) * 8));        \
    }                                                                          \
    STAGE_STMT;                                                                \
    LGKM0;                                                                     \
    WAIT_STMT;                                                                 \
    wg_barrier();                                                              \
    __builtin_amdgcn_s_setprio(1);                                             \
    _Pragma("unroll")                                                          \
    for (int f = 0; f < 2; f++)                                                \
      _Pragma("unroll")                                                        \
      for (int g = 0; g < 2; g++)                                              \
        _Pragma("unroll")                                                      \
        for (int ks = 0; ks < 2; ks++)                                         \
          acc[(MH) * 2 + f][(NH) * 2 + g] =                                    \
              __builtin_amdgcn_mfma_f32_16x16x32_f16(                          \
                  af[f][ks], bf[g][ks], acc[(MH) * 2 + f][(NH) * 2 + g],       \
                  0, 0, 0);                                                    \
    __builtin_amdgcn_s_setprio(0);                                             \
  }

__global__ __launch_bounds__(512, 2) void gemm_8ph(
    const _Float16* __restrict__ Ah, const _Float16* __restrict__ Bh,
    const float* __restrict__ b_all, _Float16* __restrict__ pre16) {
  // 96 KB: 2 bufs x (A 8192 + B 16384 halfs). Epilogue reuses first 67584 B.
  __shared__ __attribute__((aligned(16))) _Float16 lds[49152];

  // Bijective XCD swizzle: 768 blocks = 8 XCDs x 96. Within a chunk: B-panel
  // major (nTile constant over 32 consecutive blocks -> 1 MB B panel hot in L2).
  const int bid = blockIdx.x;
  const int swz = (bid & 7) * 96 + (bid >> 3);
  const int nTile = swz / 32;   // 0..23
  const int mTile = swz % 32;   // 0..31

  const int t = threadIdx.x;
  const int lane = t & 63;
  const int wave = t >> 6;
  const int wm = wave >> 2, wn = wave & 3;       // 2 x 4 waves
  const int kgrp = lane >> 4, frow = lane & 15;

  const _Float16* Abase = Ah + (size_t)mTile * 128 * 2048;
  const _Float16* Bbase = Bh + (size_t)nTile * 256 * 2048;

  f32x4 acc[4][4] = {};

  // Stage one A-half (64 rows x 64 k = 8 KB): 1 load/thread. LDS dest linear
  // (wave-uniform base + lane*16); XOR swizzle folded into the GLOBAL source.
  auto stageA = [&](int kt, int mh) {
    int r = t >> 3, k8 = t & 7;
    int xs = k8 ^ (r & 7);
    const _Float16* g = Abase + (size_t)(mh * 64 + r) * 2048 + kt * 64 + xs * 8;
    _Float16* l = lds + (kt & 1) * 24576 + mh * 4096 + t * 8;
    async16(g, l);
  };
  // Stage one B-half (128 rows x 64 k = 16 KB): 2 loads/thread.
  auto stageB = [&](int kt, int nh) {
#pragma unroll
    for (int q = 0; q < 2; q++) {
      int s = q * 512 + t;
      int r = s >> 3, k8 = s & 7;
      int xs = k8 ^ (r & 7);
      const _Float16* g = Bbase + (size_t)(nh * 128 + r) * 2048 + kt * 64 + xs * 8;
      _Float16* l = lds + (kt & 1) * 24576 + 8192 + nh * 8192 + s * 8;
      async16(g, l);
    }
  };

  // Prologue: K0 fully + K1.{A0,B0} (steady-state issue order) = 9 loads;
  // vmcnt(3) leaves K1.A0+K1.B0 in flight, all of K0 landed.
  stageA(0, 0); stageB(0, 0); stageA(0, 1); stageB(0, 1);
  stageA(1, 0); stageB(1, 0);
  asm volatile("s_waitcnt vmcnt(3)" ::: "memory");
  wg_barrier();

  // Main loop. Per K-tile T (4 phases = 4 quadrants):
  //   p0 (A0,B0): stage (T+1).A1   [other buf; tenant T-1 last read its p3]
  //   p1 (A0,B1): stage (T+1).B1   [other buf; tenant T-1 last read its p3]
  //   p2 (A1,B0): stage (T+2).A0   [this buf; A0 last read p1, all waves past
  //                                 p1's barrier before any issues this stage]
  //   p3 (A1,B1): stage (T+2).B0   [this buf; B0 last read p2]
  //   p3 wait: vmcnt(3) -> all of T+1 landed, (T+2).{A0,B0} still in flight.
  //   Last two tiles: vmcnt(0) (their successors' stages were skipped).
#pragma unroll 2
  for (int T = 0; T < 32; T++) {
    PHASE(T, 0, 0, { if (T + 1 < 32) stageA(T + 1, 1); }, {});
    PHASE(T, 0, 1, { if (T + 1 < 32) stageB(T + 1, 1); }, {});
    PHASE(T, 1, 0, { if (T + 2 < 32) stageA(T + 2, 0); }, {});
    PHASE(T, 1, 1, { if (T + 2 < 32) stageB(T + 2, 0); },
          { if (T < 30) { asm volatile("s_waitcnt vmcnt(3)" ::: "memory"); }
            else        { asm volatile("s_waitcnt vmcnt(0)" ::: "memory"); } });
  }

  // Epilogue: stage fp16 tile in LDS [128][264] (pad -> <=2-way banks, rows
  // 16B-aligned), then coalesced half8 stores. All global_load_lds drained
  // (T=30 used vmcnt(0)); all main-loop LDS reads completed before the T=31
  // p3 barrier. __syncthreads() (NOT raw s_barrier) so the cross-wave ds_write
  // -> ds_read handoff is lgkmcnt-drained; vmcnt is already 0 (free).
  const float inv64 = 1.0f / 64.0f;
  const int cb = nTile * 256;
  float bias[4];
#pragma unroll
  for (int nj = 0; nj < 4; nj++) {
    int col = (nj >> 1) * 128 + wn * 32 + (nj & 1) * 16 + frow;
    bias[nj] = b_all[cb + col];
  }
#pragma unroll
  for (int mi = 0; mi < 4; mi++) {
#pragma unroll
    for (int nj = 0; nj < 4; nj++) {
      int row = (mi >> 1) * 64 + wm * 32 + (mi & 1) * 16 + kgrp * 4;
      int col = (nj >> 1) * 128 + wn * 32 + (nj & 1) * 16 + frow;
#pragma unroll
      for (int j = 0; j < 4; j++)
        lds[(row + j) * 264 + col] =
            (_Float16)(acc[mi][nj][j] * inv64 + bias[nj]);
    }
  }
  __syncthreads();
#pragma unroll
  for (int rr = 0; rr < 8; rr++) {
    int L = rr * 4096 + t * 8;
    int row = L >> 8, col = L & 255;
    half8 v = *(const half8*)(lds + row * 264 + col);
    *(half8*)(pre16 + (size_t)(mTile * 128 + row) * 6144 + cb + col) = v;
  }
}

// ---------------------------------------------------------------------------
// Row softmax over zft/zit (fp16 in pre16, cols 4096..6143), p written back in
// place (fp16) + per-chunk column sums into transposed part4. (unchanged)
__global__ void softmax_partials(_Float16* __restrict__ pre16, f32x4* __restrict__ part4) {
  __shared__ float wsum[4][1024];
  int m = blockIdx.x >> 9;
  int ch = blockIdx.x & 511;
  int t = threadIdx.x;
  int wave = t >> 6, lane = t & 63;
  f32x4 colacc[4] = {};
  for (int rr = 0; rr < 2; rr++) {
    int b = ch * 8 + wave * 2 + rr;
    _Float16* row = pre16 + (size_t)b * 6144 + (4 + m) * 1024;
    f32x4 v[4];
    float mx = -3.4e38f;
#pragma unroll
    for (int j = 0; j < 4; j++) {
      half4v h = *(const half4v*)(row + lane * 4 + 256 * j);
      v[j] = f32x4{ (float)h[0], (float)h[1], (float)h[2], (float)h[3] };
      mx = fmaxf(mx, fmaxf(fmaxf(v[j][0], v[j][1]), fmaxf(v[j][2], v[j][3])));
    }
#pragma unroll
    for (int off = 32; off > 0; off >>= 1) mx = fmaxf(mx, __shfl_xor(mx, off, 64));
    float sum = 0.f;
#pragma unroll
    for (int j = 0; j < 4; j++)
#pragma unroll
      for (int q = 0; q < 4; q++) { v[j][q] = __expf(v[j][q] - mx); sum += v[j][q]; }
#pragma unroll
    for (int off = 32; off > 0; off >>= 1) sum += __shfl_xor(sum, off, 64);
    float inv = 1.f / sum;
#pragma unroll
    for (int j = 0; j < 4; j++) {
      v[j] *= inv;
      half4v h = { (_Float16)v[j][0], (_Float16)v[j][1], (_Float16)v[j][2], (_Float16)v[j][3] };
      *(half4v*)(row + lane * 4 + 256 * j) = h;
      colacc[j] += v[j];
    }
  }
#pragma unroll
  for (int j = 0; j < 4; j++)
    *(f32x4*)(&wsum[wave][lane * 4 + 256 * j]) = colacc[j];
  __syncthreads();
  f32x4 s = *(const f32x4*)(&wsum[0][t * 4]);
  s += *(const f32x4*)(&wsum[1][t * 4]);
  s += *(const f32x4*)(&wsum[2][t * 4]);
  s += *(const f32x4*)(&wsum[3][t * 4]);
  part4[((size_t)m * 256 + t) * 512 + ch] = s;
}

// Exclusive scan over 512 chunks per (m, c4-group). (unchanged)
__global__ void scan_partials(const f32x4* __restrict__ part4, f32x4* __restrict__ off4) {
  int gidx = blockIdx.x * 4 + (threadIdx.x >> 6);
  int lane = threadIdx.x & 63;
  size_t base = (size_t)gidx * 512;
  f32x4 v[8];
  f32x4 s = {};
#pragma unroll
  for (int j = 0; j < 8; j++) {
    v[j] = part4[base + lane * 8 + j];
    s += v[j];
  }
  f32x4 incl = s;
#pragma unroll
  for (int off = 1; off < 64; off <<= 1) {
    f32x4 o;
#pragma unroll
    for (int q = 0; q < 4; q++) o[q] = __shfl_up(incl[q], off, 64);
    if (lane >= off) incl += o;
  }
  f32x4 run = incl - s;
#pragma unroll
  for (int j = 0; j < 8; j++) {
    off4[base + lane * 8 + j] = run;
    run += v[j];
  }
}

// Final: gates + cumsum + cell/hidden. (unchanged)
__global__ void onlstm_final(const _Float16* __restrict__ pre16,
                             const float* __restrict__ cprev, const f32x4* __restrict__ off4,
                             float* __restrict__ out) {
  int ch = blockIdx.x;
  int c4 = threadIdx.x;
  int c = c4 * 4;
  f32x4 runf = off4[(size_t)c4 * 512 + ch];
  f32x4 runi = off4[(size_t)(256 + c4) * 512 + ch];
  for (int r = 0; r < 8; r++) {
    int b = ch * 8 + r;
    const _Float16* row = pre16 + (size_t)b * 6144;
    half4v zf = *(const half4v*)(row + c);
    half4v zi = *(const half4v*)(row + 1024 + c);
    half4v zo = *(const half4v*)(row + 2048 + c);
    half4v zc = *(const half4v*)(row + 3072 + c);
    half4v pf = *(const half4v*)(row + 4096 + c);
    half4v pi = *(const half4v*)(row + 5120 + c);
    f32x4 cp = *(const f32x4*)(cprev + (size_t)b * 1024 + c);
    f32x4 hid, cel;
#pragma unroll
    for (int q = 0; q < 4; q++) {
      runf[q] += (float)pf[q];
      runi[q] += (float)pi[q];
      float ft = runf[q], it = 1.f - runi[q];
      float f  = 1.f / (1.f + __expf(-(float)zf[q]));
      float ii = 1.f / (1.f + __expf(-(float)zi[q]));
      float o  = 1.f / (1.f + __expf(-(float)zo[q]));
      float chat = tanhf((float)zc[q]);
      float omega = ft * it;
      float fhat = f * omega + (ft - omega);
      float ihat = ii * omega + (it - omega);
      float cell = fhat * cp[q] + ihat * chat;
      hid[q] = o * tanhf(cell);
      cel[q] = cell;
    }
    *(f32x4*)(out + (size_t)b * 1024 + c) = hid;
    *(f32x4*)(out + (size_t)4194304 + (size_t)b * 1024 + c) = cel;
  }
}

// ---------------------------------------------------------------------------
extern "C" void kernel_launch(void* const* d_in, const int* in_sizes, int n_in,
                              void* d_out, int out_size, void* d_ws, size_t ws_size,
                              hipStream_t stream) {
  const float* X = (const float*)d_in[0];
  const float* H = (const float*)d_in[1];
  const float* C = (const float*)d_in[2];

  char* ws = (char*)d_ws;
  _Float16* pre16 = (_Float16*)(ws);                      // 48 MB [4096][6144]
  _Float16* Ahi   = (_Float16*)(ws + 50331648);           // 16 MB
  _Float16* Bhi   = (_Float16*)(ws + 67108864);           // 24 MB
  float*    b_all = (float*)(ws + 92274688);              // 24 KB
  f32x4*    part4 = (f32x4*)(ws + 92299264);              //  4 MB
  f32x4*    off4  = (f32x4*)(ws + 96493568);              //  4 MB

  Ptrs12 w;
  for (int g = 0; g < 6; g++) {
    w.p[2 * g]     = (const float*)d_in[3 + 3 * g];
    w.p[2 * g + 1] = (const float*)d_in[4 + 3 * g];
  }
  Ptrs6 bs;
  for (int g = 0; g < 6; g++) bs.p[g] = (const float*)d_in[5 + 3 * g];

  prep<<<11288, 256, 0, stream>>>(X, H, w, bs, Ahi, Bhi, b_all);
  gemm_8ph<<<768, 512, 0, stream>>>(Ahi, Bhi, b_all, pre16);
  softmax_partials<<<1024, 256, 0, stream>>>(pre16, part4);
  scan_partials<<<128, 256, 0, stream>>>(part4, off4);
  onlstm_final<<<512, 256, 0, stream>>>(pre16, C, off4, (float*)d_out);
}

// Round 3
// 314.445 us; speedup vs baseline: 1.0770x; 1.0488x over previous
//
#include <hip/hip_runtime.h>
#include <cstdint>
#include <cstddef>

// ONLSTM cell: B=4096, D=1024, U=1024.
// pre16 = fp16([X|H] @ [[W_all],[U_all]] + b_all), single-fp16 MFMA.
// R1-R6 history: absmax (0.25) dominated by fp32 softmax/cumsum path; threshold 1.55.
// R8: 8-phase/counted-vmcnt (4 barriers/K-tile): 123us, MfmaUtil 37%, bank conf 0.
// R9 (this round): collapse to ONE barrier per K-tile via triple-buffered ring.
//   - LDS 3 x 48KB tile bufs (A 128x64 + B 256x64) = 144 KB.
//   - iter T: read 16 frags from buf(T%3); stage tile T+2 into buf((T+2)%3)
//     (6 global_load_lds/thread); MFMA ks0 (16); lgkm0; vmcnt(6); s_barrier;
//     MFMA ks1 (16). Distance-2 ring => stages never touch the buffer being
//     read; ONE vmcnt+barrier per tile (vmcnt(6) = tile T+1 landed, tile T+2's
//     6 loads stay in flight; vmcnt(0) only at T==30).
//   - ks-split MFMA around the barrier: next tile's ds_reads interleave into
//     the ks1 MFMA stream -> read latency hidden on both sides.
//   - R8's 4 lgkmcnt(0)+barrier per tile exposed ~150cy ds latency x4 with only
//     2 waves/SIMD; this cuts sync count 4x and doubles cluster size.
// Numerics identical (same fp16 data, same ks0->ks1 ascending-tile MFMA order).

typedef _Float16 half8  __attribute__((ext_vector_type(8)));
typedef _Float16 half4v __attribute__((ext_vector_type(4)));
typedef float f32x4 __attribute__((ext_vector_type(4)));

__device__ __forceinline__ void async16(const _Float16* g, _Float16* l) {
  __builtin_amdgcn_global_load_lds(
      (const __attribute__((address_space(1))) void*)g,
      (__attribute__((address_space(3))) void*)l, 16, 0, 0);
}

struct Ptrs12 { const float* p[12]; };
struct Ptrs6  { const float* p[6];  };

// ---------------------------------------------------------------------------
// Merged prep: convert A (X|H -> fp16), convert+transpose B (x64 scale, fp16),
// build bias. Branch is block-uniform. (unchanged from R6)
__global__ void prep(const float* __restrict__ X, const float* __restrict__ H,
                     Ptrs12 w, Ptrs6 bs,
                     _Float16* __restrict__ Ahi, _Float16* __restrict__ Bhi,
                     float* __restrict__ b_all) {
  __shared__ float tile[64][65];
  const int blk = blockIdx.x;
  const int t = threadIdx.x;
  if (blk < 8192) {
    size_t base = ((size_t)blk * 256 + t) * 4;
    int k = (int)(base & 2047);
    size_t b = base >> 11;
    const float* src = (k < 1024) ? (X + b * 1024 + k) : (H + b * 1024 + (k - 1024));
    float4 v = *(const float4*)src;
    half4v hi = { (_Float16)v.x, (_Float16)v.y, (_Float16)v.z, (_Float16)v.w };
    *(half4v*)(Ahi + base) = hi;
  } else if (blk < 11264) {
    int bb = blk - 8192;
    int mat = bb >> 8;
    int tl = bb & 255;
    int tr = tl >> 4, tc = tl & 15;
    int g = mat >> 1, s = mat & 1;
    const float* src = w.p[mat];
    int col = t & 63, r0 = t >> 6;
#pragma unroll
    for (int i = 0; i < 16; i++) {
      int row = i * 4 + r0;
      tile[row][col] = src[(size_t)(tr * 64 + row) * 1024 + tc * 64 + col];
    }
    __syncthreads();
    int c2 = t >> 2, kseg = t & 3;
    half8 v0, v1;
#pragma unroll
    for (int j = 0; j < 8; j++) {
      v0[j] = (_Float16)(tile[kseg * 16 + j][c2] * 64.0f);
      v1[j] = (_Float16)(tile[kseg * 16 + 8 + j][c2] * 64.0f);
    }
    size_t n  = (size_t)g * 1024 + tc * 64 + c2;
    size_t kk = (size_t)s * 1024 + tr * 64 + kseg * 16;
    *(half8*)(Bhi + n * 2048 + kk) = v0;
    *(half8*)(Bhi + n * 2048 + kk + 8) = v1;
  } else {
    int n = (blk - 11264) * 256 + t;
    b_all[n] = bs.p[n >> 10][n & 1023];
  }
}

// ---------------------------------------------------------------------------
// GEMM: A[4096,2048] @ Bt[6144,2048]^T / 64 + bias -> pre16 (fp16, row-major).
// Triple-buffer ring, 1 barrier/K-tile; see header comment.

#define LGKM0 asm volatile("s_waitcnt lgkmcnt(0)" ::: "memory")

__device__ __forceinline__ void wg_barrier() {
  __builtin_amdgcn_s_barrier();
  asm volatile("" ::: "memory");
}

__global__ __launch_bounds__(512, 2) void gemm_ring(
    const _Float16* __restrict__ Ah, const _Float16* __restrict__ Bh,
    const float* __restrict__ b_all, _Float16* __restrict__ pre16) {
  // 3 bufs x 24576 halfs (A 8192 + B 16384) = 144 KB. Epilogue reuses 66 KB.
  __shared__ __attribute__((aligned(16))) _Float16 lds[73728];

  // Bijective XCD swizzle: 768 blocks = 8 XCDs x 96. Within a chunk: B-panel
  // major (nTile constant over 32 consecutive blocks -> 1 MB B panel hot in L2).
  const int bid = blockIdx.x;
  const int swz = (bid & 7) * 96 + (bid >> 3);
  const int nTile = swz / 32;   // 0..23
  const int mTile = swz % 32;   // 0..31

  const int t = threadIdx.x;
  const int lane = t & 63;
  const int wave = t >> 6;
  const int wm = wave >> 2, wn = wave & 3;       // 2 x 4 waves; per-wave 64x64
  const int kgrp = lane >> 4, frow = lane & 15;

  const _Float16* Abase = Ah + (size_t)mTile * 128 * 2048;
  const _Float16* Bbase = Bh + (size_t)nTile * 256 * 2048;

  f32x4 acc[4][4] = {};

  // Stage one full K-tile (A 128x64 = 16KB -> 2 loads/thr; B 256x64 = 32KB ->
  // 4 loads/thr). LDS dest linear (wave-uniform base + lane*16); XOR slot
  // swizzle (slot ^= row&7) folded into the GLOBAL source address.
  auto stage_tile = [&](int kt, int base) {
#pragma unroll
    for (int q = 0; q < 2; q++) {
      int s = q * 512 + t;
      int r = s >> 3, k8 = s & 7;
      int xs = k8 ^ (r & 7);
      async16(Abase + (size_t)r * 2048 + kt * 64 + xs * 8, lds + base + s * 8);
    }
#pragma unroll
    for (int q = 0; q < 4; q++) {
      int s = q * 512 + t;
      int r = s >> 3, k8 = s & 7;
      int xs = k8 ^ (r & 7);
      async16(Bbase + (size_t)r * 2048 + kt * 64 + xs * 8,
              lds + base + 8192 + s * 8);
    }
  };

  // Rotating ring offsets (in halfs).
  int cur = 0, nxt = 24576, nn = 49152;

  // Prologue: stage tiles 0,1. vmcnt(6) -> tile0 landed (tile1's 6 in flight).
  stage_tile(0, cur);
  stage_tile(1, nxt);
  asm volatile("s_waitcnt vmcnt(6)" ::: "memory");
  wg_barrier();

  for (int T = 0; T < 32; T++) {
    const _Float16* A_ = lds + cur;
    const _Float16* B_ = lds + cur + 8192;
    half8 af[4][2], bf[4][2];
#pragma unroll
    for (int mi = 0; mi < 4; mi++) {
      int r = wm * 64 + mi * 16 + frow;
#pragma unroll
      for (int ks = 0; ks < 2; ks++)
        af[mi][ks] = *(const half8*)(A_ + r * 64 +
                                     (((ks * 4 + kgrp) ^ (r & 7)) * 8));
    }
#pragma unroll
    for (int nj = 0; nj < 4; nj++) {
      int r = wn * 64 + nj * 16 + frow;
#pragma unroll
      for (int ks = 0; ks < 2; ks++)
        bf[nj][ks] = *(const half8*)(B_ + r * 64 +
                                     (((ks * 4 + kgrp) ^ (r & 7)) * 8));
    }
    if (T + 2 < 32) stage_tile(T + 2, nn);

    // ks0 cluster (16 MFMA) — overlaps the ks1 read returns.
    __builtin_amdgcn_s_setprio(1);
#pragma unroll
    for (int mi = 0; mi < 4; mi++)
#pragma unroll
      for (int nj = 0; nj < 4; nj++)
        acc[mi][nj] = __builtin_amdgcn_mfma_f32_16x16x32_f16(
            af[mi][0], bf[nj][0], acc[mi][nj], 0, 0, 0);
    __builtin_amdgcn_s_setprio(0);

    // Drain my ds_reads (so buf(cur) is overwrite-safe once ALL waves pass the
    // barrier), prove tile T+1 landed (vmcnt(6): only T+2's 6 loads remain).
    LGKM0;
    if (T < 30) {
      asm volatile("s_waitcnt vmcnt(6)" ::: "memory");
      wg_barrier();
    } else if (T == 30) {
      asm volatile("s_waitcnt vmcnt(0)" ::: "memory");
      wg_barrier();
    }

    // ks1 cluster (16 MFMA) — next iteration's ds_reads interleave into this.
    __builtin_amdgcn_s_setprio(1);
#pragma unroll
    for (int mi = 0; mi < 4; mi++)
#pragma unroll
      for (int nj = 0; nj < 4; nj++)
        acc[mi][nj] = __builtin_amdgcn_mfma_f32_16x16x32_f16(
            af[mi][1], bf[nj][1], acc[mi][nj], 0, 0, 0);
    __builtin_amdgcn_s_setprio(0);

    int tmp = cur; cur = nxt; nxt = nn; nn = tmp;
  }

  // Epilogue: tile31 lived at ring index 1 (bytes 49152..98303) which overlaps
  // the 66KB C-staging region -> full __syncthreads() (lgkmcnt-drained) before
  // overwriting. Then stage fp16 C-tile [128][264] (padded) and store half8.
  __syncthreads();
  const float inv64 = 1.0f / 64.0f;
  const int cb = nTile * 256;
  float bias[4];
#pragma unroll
  for (int nj = 0; nj < 4; nj++)
    bias[nj] = b_all[cb + wn * 64 + nj * 16 + frow];
#pragma unroll
  for (int mi = 0; mi < 4; mi++) {
#pragma unroll
    for (int nj = 0; nj < 4; nj++) {
      int row = wm * 64 + mi * 16 + kgrp * 4;
      int col = wn * 64 + nj * 16 + frow;
#pragma unroll
      for (int j = 0; j < 4; j++)
        lds[(row + j) * 264 + col] =
            (_Float16)(acc[mi][nj][j] * inv64 + bias[nj]);
    }
  }
  __syncthreads();
#pragma unroll
  for (int rr = 0; rr < 8; rr++) {
    int L = rr * 4096 + t * 8;
    int row = L >> 8, col = L & 255;
    half8 v = *(const half8*)(lds + row * 264 + col);
    *(half8*)(pre16 + (size_t)(mTile * 128 + row) * 6144 + cb + col) = v;
  }
}

// ---------------------------------------------------------------------------
// Row softmax over zft/zit (fp16 in pre16, cols 4096..6143), p written back in
// place (fp16) + per-chunk column sums into transposed part4. (unchanged)
__global__ void softmax_partials(_Float16* __restrict__ pre16, f32x4* __restrict__ part4) {
  __shared__ float wsum[4][1024];
  int m = blockIdx.x >> 9;
  int ch = blockIdx.x & 511;
  int t = threadIdx.x;
  int wave = t >> 6, lane = t & 63;
  f32x4 colacc[4] = {};
  for (int rr = 0; rr < 2; rr++) {
    int b = ch * 8 + wave * 2 + rr;
    _Float16* row = pre16 + (size_t)b * 6144 + (4 + m) * 1024;
    f32x4 v[4];
    float mx = -3.4e38f;
#pragma unroll
    for (int j = 0; j < 4; j++) {
      half4v h = *(const half4v*)(row + lane * 4 + 256 * j);
      v[j] = f32x4{ (float)h[0], (float)h[1], (float)h[2], (float)h[3] };
      mx = fmaxf(mx, fmaxf(fmaxf(v[j][0], v[j][1]), fmaxf(v[j][2], v[j][3])));
    }
#pragma unroll
    for (int off = 32; off > 0; off >>= 1) mx = fmaxf(mx, __shfl_xor(mx, off, 64));
    float sum = 0.f;
#pragma unroll
    for (int j = 0; j < 4; j++)
#pragma unroll
      for (int q = 0; q < 4; q++) { v[j][q] = __expf(v[j][q] - mx); sum += v[j][q]; }
#pragma unroll
    for (int off = 32; off > 0; off >>= 1) sum += __shfl_xor(sum, off, 64);
    float inv = 1.f / sum;
#pragma unroll
    for (int j = 0; j < 4; j++) {
      v[j] *= inv;
      half4v h = { (_Float16)v[j][0], (_Float16)v[j][1], (_Float16)v[j][2], (_Float16)v[j][3] };
      *(half4v*)(row + lane * 4 + 256 * j) = h;
      colacc[j] += v[j];
    }
  }
#pragma unroll
  for (int j = 0; j < 4; j++)
    *(f32x4*)(&wsum[wave][lane * 4 + 256 * j]) = colacc[j];
  __syncthreads();
  f32x4 s = *(const f32x4*)(&wsum[0][t * 4]);
  s += *(const f32x4*)(&wsum[1][t * 4]);
  s += *(const f32x4*)(&wsum[2][t * 4]);
  s += *(const f32x4*)(&wsum[3][t * 4]);
  part4[((size_t)m * 256 + t) * 512 + ch] = s;
}

// Exclusive scan over 512 chunks per (m, c4-group). (unchanged)
__global__ void scan_partials(const f32x4* __restrict__ part4, f32x4* __restrict__ off4) {
  int gidx = blockIdx.x * 4 + (threadIdx.x >> 6);
  int lane = threadIdx.x & 63;
  size_t base = (size_t)gidx * 512;
  f32x4 v[8];
  f32x4 s = {};
#pragma unroll
  for (int j = 0; j < 8; j++) {
    v[j] = part4[base + lane * 8 + j];
    s += v[j];
  }
  f32x4 incl = s;
#pragma unroll
  for (int off = 1; off < 64; off <<= 1) {
    f32x4 o;
#pragma unroll
    for (int q = 0; q < 4; q++) o[q] = __shfl_up(incl[q], off, 64);
    if (lane >= off) incl += o;
  }
  f32x4 run = incl - s;
#pragma unroll
  for (int j = 0; j < 8; j++) {
    off4[base + lane * 8 + j] = run;
    run += v[j];
  }
}

// Final: gates + cumsum + cell/hidden. (unchanged)
__global__ void onlstm_final(const _Float16* __restrict__ pre16,
                             const float* __restrict__ cprev, const f32x4* __restrict__ off4,
                             float* __restrict__ out) {
  int ch = blockIdx.x;
  int c4 = threadIdx.x;
  int c = c4 * 4;
  f32x4 runf = off4[(size_t)c4 * 512 + ch];
  f32x4 runi = off4[(size_t)(256 + c4) * 512 + ch];
  for (int r = 0; r < 8; r++) {
    int b = ch * 8 + r;
    const _Float16* row = pre16 + (size_t)b * 6144;
    half4v zf = *(const half4v*)(row + c);
    half4v zi = *(const half4v*)(row + 1024 + c);
    half4v zo = *(const half4v*)(row + 2048 + c);
    half4v zc = *(const half4v*)(row + 3072 + c);
    half4v pf = *(const half4v*)(row + 4096 + c);
    half4v pi = *(const half4v*)(row + 5120 + c);
    f32x4 cp = *(const f32x4*)(cprev + (size_t)b * 1024 + c);
    f32x4 hid, cel;
#pragma unroll
    for (int q = 0; q < 4; q++) {
      runf[q] += (float)pf[q];
      runi[q] += (float)pi[q];
      float ft = runf[q], it = 1.f - runi[q];
      float f  = 1.f / (1.f + __expf(-(float)zf[q]));
      float ii = 1.f / (1.f + __expf(-(float)zi[q]));
      float o  = 1.f / (1.f + __expf(-(float)zo[q]));
      float chat = tanhf((float)zc[q]);
      float omega = ft * it;
      float fhat = f * omega + (ft - omega);
      float ihat = ii * omega + (it - omega);
      float cell = fhat * cp[q] + ihat * chat;
      hid[q] = o * tanhf(cell);
      cel[q] = cell;
    }
    *(f32x4*)(out + (size_t)b * 1024 + c) = hid;
    *(f32x4*)(out + (size_t)4194304 + (size_t)b * 1024 + c) = cel;
  }
}

// ---------------------------------------------------------------------------
extern "C" void kernel_launch(void* const* d_in, const int* in_sizes, int n_in,
                              void* d_out, int out_size, void* d_ws, size_t ws_size,
                              hipStream_t stream) {
  const float* X = (const float*)d_in[0];
  const float* H = (const float*)d_in[1];
  const float* C = (const float*)d_in[2];

  char* ws = (char*)d_ws;
  _Float16* pre16 = (_Float16*)(ws);                      // 48 MB [4096][6144]
  _Float16* Ahi   = (_Float16*)(ws + 50331648);           // 16 MB
  _Float16* Bhi   = (_Float16*)(ws + 67108864);           // 24 MB
  float*    b_all = (float*)(ws + 92274688);              // 24 KB
  f32x4*    part4 = (f32x4*)(ws + 92299264);              //  4 MB
  f32x4*    off4  = (f32x4*)(ws + 96493568);              //  4 MB

  Ptrs12 w;
  for (int g = 0; g < 6; g++) {
    w.p[2 * g]     = (const float*)d_in[3 + 3 * g];
    w.p[2 * g + 1] = (const float*)d_in[4 + 3 * g];
  }
  Ptrs6 bs;
  for (int g = 0; g < 6; g++) bs.p[g] = (const float*)d_in[5 + 3 * g];

  prep<<<11288, 256, 0, stream>>>(X, H, w, bs, Ahi, Bhi, b_all);
  gemm_ring<<<768, 512, 0, stream>>>(Ahi, Bhi, b_all, pre16);
  softmax_partials<<<1024, 256, 0, stream>>>(pre16, part4);
  scan_partials<<<128, 256, 0, stream>>>(part4, off4);
  onlstm_final<<<512, 256, 0, stream>>>(pre16, C, off4, (float*)d_out);
}